// Round 5
// baseline (814.232 us; speedup 1.0000x reference)
//
#include <hip/hip_runtime.h>

// ---------- types ----------
typedef __attribute__((ext_vector_type(8))) short bf16x8;   // 8 bf16 = 4 VGPRs
typedef __attribute__((ext_vector_type(4))) float f32x4;    // MFMA 16x16 acc

__device__ __forceinline__ unsigned short f2bf(float f) {
    union { float f; unsigned int u; } v; v.f = f;
    unsigned int u = v.u;
    u += 0x7fffu + ((u >> 16) & 1u);   // round-to-nearest-even
    return (unsigned short)(u >> 16);
}
__device__ __forceinline__ float bf2f(unsigned short s) {
    union { unsigned int u; float f; } v; v.u = ((unsigned int)s) << 16;
    return v.f;
}

// ---------- dtype probe: flag=1 if inputs are fp32, 0 if bf16 ----------
__global__ __launch_bounds__(256) void detect_dtype(
    const unsigned short* __restrict__ x, int* __restrict__ flag) {
    __shared__ int red[4];
    const int t = threadIdx.x;
    int cnt = 0;
    #pragma unroll
    for (int i = 0; i < 16; i++) {
        const unsigned short v = x[t * 16 + i];
        const int e = (v >> 7) & 0xFF;
        cnt += (e >= 0xC8) ? 1 : 0;
    }
    #pragma unroll
    for (int off = 32; off; off >>= 1) cnt += __shfl_down(cnt, off);
    if ((t & 63) == 0) red[t >> 6] = cnt;
    __syncthreads();
    if (t == 0) *flag = (red[0] + red[1] + red[2] + red[3] >= 16) ? 1 : 0;
}

// ---------- x -> bf16 copy/convert ----------
__global__ __launch_bounds__(256) void convert_x(
    const void* __restrict__ xin, unsigned short* __restrict__ xb,
    const int* __restrict__ flag) {
    const long i = ((long)blockIdx.x * 256 + threadIdx.x) * 4;
    if (*flag) {
        const float4 v = *(const float4*)((const float*)xin + i);
        unsigned long long pk =  (unsigned long long)f2bf(v.x)
                              | ((unsigned long long)f2bf(v.y) << 16)
                              | ((unsigned long long)f2bf(v.z) << 32)
                              | ((unsigned long long)f2bf(v.w) << 48);
        *(unsigned long long*)(xb + i) = pk;
    } else {
        *(unsigned long long*)(xb + i) =
            *(const unsigned long long*)((const unsigned short*)xin + i);
    }
}

// ---------- weight transpose+convert ----------
__global__ __launch_bounds__(256) void transpose_convert(
    const void* __restrict__ W, unsigned short* __restrict__ Wt,
    const int* __restrict__ flag) {
    __shared__ unsigned short tile[32][33];
    const int tx = threadIdx.x & 31, ty = threadIdx.x >> 5;
    const int x0 = blockIdx.x * 32, y0 = blockIdx.y * 32;
    const int f = *flag;
    #pragma unroll
    for (int i = 0; i < 32; i += 8) {
        const long idx = (long)(y0 + ty + i) * 1024 + x0 + tx;
        tile[ty + i][tx] = f ? f2bf(((const float*)W)[idx])
                             : ((const unsigned short*)W)[idx];
    }
    __syncthreads();
    #pragma unroll
    for (int i = 0; i < 32; i += 8)
        Wt[(long)(x0 + ty + i) * 1024 + y0 + tx] = tile[tx][ty + i];
}

// ---------- 1024-vec -> bf16 ----------
__global__ __launch_bounds__(256) void convert_vec1024(
    const void* __restrict__ in, unsigned short* __restrict__ outv,
    const int* __restrict__ flag) {
    const int i = threadIdx.x * 4;
    if (*flag) {
        const float4 v = *(const float4*)((const float*)in + i);
        outv[i] = f2bf(v.x); outv[i+1] = f2bf(v.y);
        outv[i+2] = f2bf(v.z); outv[i+3] = f2bf(v.w);
    } else {
        *(unsigned long long*)(outv + i) =
            *(const unsigned long long*)((const unsigned short*)in + i);
    }
}

// ---------- bf16 GEMM, BK=64, transposed output via LDS-staged coalesced store --
// C[n][m] = scale * (sum_k A[m][k]*Bt[n][k] + bias[m])   (bias row-indexed)
// 128x128 tile, 4 waves (2x2), 4x4 MFMA 16x16x32 per wave, 2 k-halves/stage.
// LDS fragment-order chunks: (r,kq) -> ((r>>4)*8+kq)*16 + (r&15); bank-even for
// staging writes and frag reads (8 lanes / 4-bank group = wave64 minimum).
#define BM 128
#define BN 128
#define BK 64

__global__ __launch_bounds__(256, 3) void gemm_bt(
    const unsigned short* __restrict__ A, const unsigned short* __restrict__ Bt,
    unsigned short* __restrict__ C,
    int K, int lda, int ldb, int ldc,
    long strideAz, long strideBz, long strideCz,
    const unsigned short* __restrict__ bias, float scale) {

    A  += (long)blockIdx.z * strideAz;
    Bt += (long)blockIdx.z * strideBz;
    C  += (long)blockIdx.z * strideCz;

    // 34,816 B: K-loop uses [0,32768) as As|Bs; epilogue reuses all as Cs (stride 136)
    __shared__ __align__(16) unsigned char smem[34816];
    unsigned short* As = (unsigned short*)smem;             // 16 KiB
    unsigned short* Bs = (unsigned short*)(smem + 16384);   // 16 KiB
    unsigned short* Cs = (unsigned short*)smem;             // epilogue

    const int t    = threadIdx.x;
    const int wave = t >> 6;
    const int lane = t & 63;
    const int quad = lane >> 4;
    const int lm   = lane & 15;

    const int m0 = blockIdx.y * BM;
    const int n0 = blockIdx.x * BN;
    const int wm = (wave >> 1) * 64;
    const int wn = (wave & 1) * 64;

    f32x4 acc[4][4];
    #pragma unroll
    for (int i = 0; i < 4; i++)
        #pragma unroll
        for (int j = 0; j < 4; j++) acc[i][j] = (f32x4){0.f, 0.f, 0.f, 0.f};

    // staging: thread t -> chunk col kq = t&7 (8 chunks of 8 bf16 per row),
    // rows r = (t>>3) + s*32, s = 0..3  (global: 8 threads = 128B contiguous)
    const int kq = t & 7;
    const int rb = t >> 3;
    const unsigned short* pa[4];
    const unsigned short* pb[4];
    int ldso[4];
    #pragma unroll
    for (int s = 0; s < 4; s++) {
        const int r = rb + s * 32;
        pa[s] = A  + (long)(m0 + r) * lda + kq * 8;
        pb[s] = Bt + (long)(n0 + r) * ldb + kq * 8;
        ldso[s] = (((r >> 4) * 8 + kq) * 16 + (r & 15)) * 8;
    }

    uint4 va[4], vb[4];
    #pragma unroll
    for (int s = 0; s < 4; s++) { va[s] = *(const uint4*)(pa[s]); vb[s] = *(const uint4*)(pb[s]); }

    for (int k0 = 0; k0 < K; k0 += BK) {
        __syncthreads();               // prior readers done with LDS
        #pragma unroll
        for (int s = 0; s < 4; s++) {
            *(uint4*)(&As[ldso[s]]) = va[s];
            *(uint4*)(&Bs[ldso[s]]) = vb[s];
        }
        __syncthreads();               // writes visible

        // prefetch next stage: in flight across the 2 MFMA half-phases below
        if (k0 + BK < K) {
            #pragma unroll
            for (int s = 0; s < 4; s++) {
                va[s] = *(const uint4*)(pa[s] + k0 + BK);
                vb[s] = *(const uint4*)(pb[s] + k0 + BK);
            }
        }

        #pragma unroll
        for (int h = 0; h < 2; h++) {
            bf16x8 af[4], bfr[4];
            #pragma unroll
            for (int i = 0; i < 4; i++)
                af[i]  = *(const bf16x8*)(&As[((((wm >> 4) + i) * 8 + h * 4 + quad) * 16 + lm) * 8]);
            #pragma unroll
            for (int j = 0; j < 4; j++)
                bfr[j] = *(const bf16x8*)(&Bs[((((wn >> 4) + j) * 8 + h * 4 + quad) * 16 + lm) * 8]);
            #pragma unroll
            for (int i = 0; i < 4; i++)
                #pragma unroll
                for (int j = 0; j < 4; j++)
                    acc[i][j] = __builtin_amdgcn_mfma_f32_16x16x32_bf16(
                        af[i], bfr[j], acc[i][j], 0, 0, 0);
        }
    }

    // ---- epilogue: C/D layout col=lane&15, row=quad*4+reg (m89-verified) ----
    // Stage tile in LDS (row-stride 136 keeps banks even), then coalesced stores.
    __syncthreads();   // all waves done reading As/Bs
    #pragma unroll
    for (int i = 0; i < 4; i++) {
        const int row = wm + i * 16 + quad * 4;       // local m
        #pragma unroll
        for (int j = 0; j < 4; j++) {
            const int col = wn + j * 16 + lm;         // local n
            unsigned long long pk = 0;
            #pragma unroll
            for (int r = 0; r < 4; r++) {
                const float b = bias ? bf2f(bias[m0 + row + r]) : 0.f;
                pk |= (unsigned long long)f2bf((acc[i][j][r] + b) * scale) << (16 * r);
            }
            *(unsigned long long*)(&Cs[col * 136 + row]) = pk;
        }
    }
    __syncthreads();
    #pragma unroll
    for (int pass = 0; pass < 8; pass++) {
        const int idx = pass * 256 + t;
        const int n  = idx >> 4;        // 0..127
        const int mc = idx & 15;        // 16B chunk within row
        const uint4 vv = *(const uint4*)(&Cs[n * 136 + mc * 8]);
        *(uint4*)(&C[(long)(n0 + n) * ldc + m0 + mc * 8]) = vv;
    }
}

// ---------- softmax ----------
__global__ __launch_bounds__(256) void softmax_rows(unsigned short* __restrict__ S, int rowlen) {
    __shared__ float red[4];
    const long row = blockIdx.x;
    unsigned short* p = S + row * rowlen;
    const int t = threadIdx.x;
    const int wave = t >> 6, lane = t & 63;

    uint4 raw = *(uint4*)(p + t * 8);
    unsigned short* u = (unsigned short*)&raw;
    float v[8], mx = -3.0e38f;
    #pragma unroll
    for (int i = 0; i < 8; i++) { v[i] = bf2f(u[i]); mx = fmaxf(mx, v[i]); }
    #pragma unroll
    for (int off = 32; off; off >>= 1) mx = fmaxf(mx, __shfl_down(mx, off));
    if (lane == 0) red[wave] = mx;
    __syncthreads();
    mx = fmaxf(fmaxf(red[0], red[1]), fmaxf(red[2], red[3]));
    __syncthreads();

    float s = 0.f;
    #pragma unroll
    for (int i = 0; i < 8; i++) { v[i] = __expf(v[i] - mx); s += v[i]; }
    #pragma unroll
    for (int off = 32; off; off >>= 1) s += __shfl_down(s, off);
    if (lane == 0) red[wave] = s;
    __syncthreads();
    s = red[0] + red[1] + red[2] + red[3];
    const float inv = 1.f / s;
    #pragma unroll
    for (int i = 0; i < 8; i++) u[i] = f2bf(v[i] * inv);
    *(uint4*)(p + t * 8) = raw;
}

// ---------- residual + LayerNorm, dual dtype ----------
__global__ __launch_bounds__(256) void resid_ln(
    const void* __restrict__ x, const unsigned short* __restrict__ attn,
    const void* __restrict__ gamma, const void* __restrict__ beta,
    void* __restrict__ out, const int* __restrict__ flag) {
    __shared__ float red[8];
    const long row = blockIdx.x;
    const int t = threadIdx.x;
    const int wave = t >> 6, lane = t & 63;
    const long base = row * 1024 + t * 4;
    const int f = *flag;

    uint2 ar = *(const uint2*)(attn + base);
    const unsigned short* au = (const unsigned short*)&ar;
    float h[4], s = 0.f, s2 = 0.f;
    if (f) {
        const float4 xr = *(const float4*)((const float*)x + base);
        h[0] = xr.x + bf2f(au[0]); h[1] = xr.y + bf2f(au[1]);
        h[2] = xr.z + bf2f(au[2]); h[3] = xr.w + bf2f(au[3]);
    } else {
        const uint2 xr = *(const uint2*)((const unsigned short*)x + base);
        const unsigned short* xu = (const unsigned short*)&xr;
        #pragma unroll
        for (int i = 0; i < 4; i++) h[i] = bf2f(xu[i]) + bf2f(au[i]);
    }
    #pragma unroll
    for (int i = 0; i < 4; i++) { s += h[i]; s2 += h[i] * h[i]; }
    #pragma unroll
    for (int off = 32; off; off >>= 1) { s += __shfl_down(s, off); s2 += __shfl_down(s2, off); }
    if (lane == 0) { red[wave] = s; red[4 + wave] = s2; }
    __syncthreads();
    s  = red[0] + red[1] + red[2] + red[3];
    s2 = red[4] + red[5] + red[6] + red[7];
    const float mu = s * (1.f / 1024.f);
    const float var = s2 * (1.f / 1024.f) - mu * mu;
    const float rstd = rsqrtf(var + 1e-3f);

    float g[4], bb[4];
    if (f) {
        const float4 gr = *(const float4*)((const float*)gamma + t * 4);
        const float4 br = *(const float4*)((const float*)beta  + t * 4);
        g[0]=gr.x; g[1]=gr.y; g[2]=gr.z; g[3]=gr.w;
        bb[0]=br.x; bb[1]=br.y; bb[2]=br.z; bb[3]=br.w;
    } else {
        #pragma unroll
        for (int i = 0; i < 4; i++) {
            g[i]  = bf2f(((const unsigned short*)gamma)[t * 4 + i]);
            bb[i] = bf2f(((const unsigned short*)beta)[t * 4 + i]);
        }
    }

    if (f) {
        float4 o;
        o.x = g[0]*(h[0]-mu)*rstd + bb[0];
        o.y = g[1]*(h[1]-mu)*rstd + bb[1];
        o.z = g[2]*(h[2]-mu)*rstd + bb[2];
        o.w = g[3]*(h[3]-mu)*rstd + bb[3];
        *(float4*)((float*)out + base) = o;
    } else {
        unsigned long long pk = 0;
        #pragma unroll
        for (int i = 0; i < 4; i++)
            pk |= (unsigned long long)f2bf(g[i]*(h[i]-mu)*rstd + bb[i]) << (16 * i);
        *(unsigned long long*)((unsigned short*)out + base) = pk;
    }
}

// ---------- launch ----------
extern "C" void kernel_launch(void* const* d_in, const int* in_sizes, int n_in,
                              void* d_out, int out_size, void* d_ws, size_t ws_size,
                              hipStream_t stream) {
    const void* x  = d_in[0];
    const void* Wq = d_in[1];
    const void* bq = d_in[2];
    const void* Wk = d_in[3];
    const void* bk = d_in[4];
    const void* Wv = d_in[5];
    const void* bv = d_in[6];
    const void* gamma = d_in[7];
    const void* beta  = d_in[8];

    // ws layout (bytes):
    //   xb / attn (reused):  0          (16,777,216)
    //   wt (Wq^T,Wk^T,Wv^T): 16,777,216 ( 6,291,456)
    //   bb (bq,bk,bv bf16):  23,068,672 (     6,144)
    //   flag:                23,074,816 (       128)
    //   qk [8192][2048]:     23,074,944 (33,554,432)  cols 0-1023=q, 1024-2047=k
    //   vt [1024][8192]:     56,629,376 (16,777,216)
    //   sc [4][2048][2048]:  73,406,592 (33,554,432)  -> end 106,961,024
    char* ws = (char*)d_ws;
    unsigned short* xb   = (unsigned short*)(ws);
    unsigned short* attn = (unsigned short*)(ws);
    unsigned short* wt   = (unsigned short*)(ws + 16777216L);
    unsigned short* bb   = (unsigned short*)(ws + 23068672L);
    int*            flag = (int*)(ws + 23074816L);
    unsigned short* qk   = (unsigned short*)(ws + 23074944L);
    unsigned short* vt   = (unsigned short*)(ws + 56629376L);
    unsigned short* sc   = (unsigned short*)(ws + 73406592L);

    const dim3 tb(256);
    detect_dtype<<<dim3(1), tb, 0, stream>>>((const unsigned short*)x, flag);
    convert_x<<<dim3(8192), tb, 0, stream>>>(x, xb, flag);
    transpose_convert<<<dim3(32, 32), tb, 0, stream>>>(Wq, wt, flag);
    transpose_convert<<<dim3(32, 32), tb, 0, stream>>>(Wk, wt + 1048576, flag);
    transpose_convert<<<dim3(32, 32), tb, 0, stream>>>(Wv, wt + 2097152, flag);
    convert_vec1024<<<dim3(1), tb, 0, stream>>>(bq, bb, flag);
    convert_vec1024<<<dim3(1), tb, 0, stream>>>(bk, bb + 1024, flag);
    convert_vec1024<<<dim3(1), tb, 0, stream>>>(bv, bb + 2048, flag);

    // Fused Q+K projection: qk[s][e'] = x @ [Wq|Wk] + [bq|bk]
    gemm_bt<<<dim3(64, 16, 1), tb, 0, stream>>>(wt, xb, qk,
        1024, 1024, 1024, 2048, 0L, 0L, 0L, bb, 1.0f);
    // V projection (transposed out): vt[d][s] = (x @ Wv)^T   (bv folded into PV)
    gemm_bt<<<dim3(8, 64, 1), tb, 0, stream>>>(xb, wt + 2097152, vt,
        1024, 1024, 1024, 8192, 0L, 0L, 0L, nullptr, 1.0f);
    // scores: sc[z][q][k] = (q_z . k_z) / 32   (A = k rows, Bt = q rows)
    gemm_bt<<<dim3(16, 16, 4), tb, 0, stream>>>(qk + 1024, qk, sc,
        1024, 2048, 2048, 2048, 4194304L, 4194304L, 4194304L, nullptr, 0.03125f);
    // P = softmax(sc) rows, in place
    softmax_rows<<<dim3(8192), tb, 0, stream>>>(sc, 2048);
    // attn[q][d] = P_z @ v_z + bv  (A = vt cols z*2048.., Bt = P rows q)
    gemm_bt<<<dim3(16, 8, 4), tb, 0, stream>>>(vt, sc, attn,
        2048, 8192, 2048, 1024, 2048L, 4194304L, 2097152L, bb + 2048, 1.0f);
    // out = LN(x + attn)
    resid_ln<<<dim3(8192), tb, 0, stream>>>(x, attn, gamma, beta, d_out, flag);
}

// Round 6
// 603.163 us; speedup vs baseline: 1.3499x; 1.3499x over previous
//
#include <hip/hip_runtime.h>

// ---------- types ----------
typedef __attribute__((ext_vector_type(8))) short bf16x8;   // 8 bf16 = 4 VGPRs
typedef __attribute__((ext_vector_type(4))) float f32x4;    // MFMA 16x16 acc

__device__ __forceinline__ unsigned short f2bf(float f) {
    union { float f; unsigned int u; } v; v.f = f;
    unsigned int u = v.u;
    u += 0x7fffu + ((u >> 16) & 1u);   // round-to-nearest-even
    return (unsigned short)(u >> 16);
}
__device__ __forceinline__ float bf2f(unsigned short s) {
    union { unsigned int u; float f; } v; v.u = ((unsigned int)s) << 16;
    return v.f;
}
// LDS chunk-index swizzle (r4-proven: 0 conflicts for staging writes AND frag reads)
__device__ __forceinline__ int swz(int p) { return p ^ ((p >> 3) & 7); }

// ---------- dtype probe: flag=1 if inputs are fp32, 0 if bf16 ----------
__global__ __launch_bounds__(256) void detect_dtype(
    const unsigned short* __restrict__ x, int* __restrict__ flag) {
    __shared__ int red[4];
    const int t = threadIdx.x;
    int cnt = 0;
    #pragma unroll
    for (int i = 0; i < 16; i++) {
        const unsigned short v = x[t * 16 + i];
        const int e = (v >> 7) & 0xFF;
        cnt += (e >= 0xC8) ? 1 : 0;
    }
    #pragma unroll
    for (int off = 32; off; off >>= 1) cnt += __shfl_down(cnt, off);
    if ((t & 63) == 0) red[t >> 6] = cnt;
    __syncthreads();
    if (t == 0) *flag = (red[0] + red[1] + red[2] + red[3] >= 16) ? 1 : 0;
}

// ---------- x -> bf16 copy/convert ----------
__global__ __launch_bounds__(256) void convert_x(
    const void* __restrict__ xin, unsigned short* __restrict__ xb,
    const int* __restrict__ flag) {
    const long i = ((long)blockIdx.x * 256 + threadIdx.x) * 4;
    if (*flag) {
        const float4 v = *(const float4*)((const float*)xin + i);
        unsigned long long pk =  (unsigned long long)f2bf(v.x)
                              | ((unsigned long long)f2bf(v.y) << 16)
                              | ((unsigned long long)f2bf(v.z) << 32)
                              | ((unsigned long long)f2bf(v.w) << 48);
        *(unsigned long long*)(xb + i) = pk;
    } else {
        *(unsigned long long*)(xb + i) =
            *(const unsigned long long*)((const unsigned short*)xin + i);
    }
}

// ---------- weight transpose+convert ----------
__global__ __launch_bounds__(256) void transpose_convert(
    const void* __restrict__ W, unsigned short* __restrict__ Wt,
    const int* __restrict__ flag) {
    __shared__ unsigned short tile[32][33];
    const int tx = threadIdx.x & 31, ty = threadIdx.x >> 5;
    const int x0 = blockIdx.x * 32, y0 = blockIdx.y * 32;
    const int f = *flag;
    #pragma unroll
    for (int i = 0; i < 32; i += 8) {
        const long idx = (long)(y0 + ty + i) * 1024 + x0 + tx;
        tile[ty + i][tx] = f ? f2bf(((const float*)W)[idx])
                             : ((const unsigned short*)W)[idx];
    }
    __syncthreads();
    #pragma unroll
    for (int i = 0; i < 32; i += 8)
        Wt[(long)(x0 + ty + i) * 1024 + y0 + tx] = tile[tx][ty + i];
}

// ---------- 1024-vec -> bf16 ----------
__global__ __launch_bounds__(256) void convert_vec1024(
    const void* __restrict__ in, unsigned short* __restrict__ outv,
    const int* __restrict__ flag) {
    const int i = threadIdx.x * 4;
    if (*flag) {
        const float4 v = *(const float4*)((const float*)in + i);
        outv[i] = f2bf(v.x); outv[i+1] = f2bf(v.y);
        outv[i+2] = f2bf(v.z); outv[i+3] = f2bf(v.w);
    } else {
        *(unsigned long long*)(outv + i) =
            *(const unsigned long long*)((const unsigned short*)in + i);
    }
}

// ---------- bf16 GEMM: r4 structure, 128x256 block tile, 64x128 wave tile -----
// C[n][m] = scale * (sum_k A[m][k]*Bt[n][k] + bias[m])   (bias row-indexed)
// 4 waves (2x2), each 4x8 MFMA 16x16x32 tiles. BK=32, swizzled fragment-order
// LDS (r4-proven conflict-free), register prefetch across the MFMA phase.
#define BM 128
#define BN 256
#define BK 32

__global__ __launch_bounds__(256, 2) void gemm_bt(
    const unsigned short* __restrict__ A, const unsigned short* __restrict__ Bt,
    unsigned short* __restrict__ C,
    int K, int lda, int ldb, int ldc,
    long strideAz, long strideBz, long strideCz,
    const unsigned short* __restrict__ bias, float scale) {

    A  += (long)blockIdx.z * strideAz;
    Bt += (long)blockIdx.z * strideBz;
    C  += (long)blockIdx.z * strideCz;

    __shared__ unsigned short As[BM * BK];   //  8 KiB, 512 chunks
    __shared__ unsigned short Bs[BN * BK];   // 16 KiB, 1024 chunks

    const int t    = threadIdx.x;
    const int wave = t >> 6;
    const int lane = t & 63;
    const int quad = lane >> 4;
    const int lm   = lane & 15;

    const int m0 = blockIdx.y * BM;
    const int n0 = blockIdx.x * BN;
    const int wm = (wave >> 1) * 64;     // wave m-offset: 0 or 64
    const int wn = (wave & 1) * 128;     // wave n-offset: 0 or 128

    f32x4 acc[4][8];
    #pragma unroll
    for (int i = 0; i < 4; i++)
        #pragma unroll
        for (int j = 0; j < 8; j++) acc[i][j] = (f32x4){0.f, 0.f, 0.f, 0.f};

    // staging: thread t -> kq = t&3, base row rr = t>>2; rows rr+64s
    // A: s=0,1 (128 rows); B: s=0..3 (256 rows)
    const int kq = t & 3;
    const int rr = t >> 2;
    const unsigned short* pa[2];
    const unsigned short* pb[4];
    int oA[2], oB[4];
    #pragma unroll
    for (int s = 0; s < 2; s++) {
        const int r = rr + s * 64;
        pa[s] = A + (long)(m0 + r) * lda + kq * 8;
        oA[s] = swz((((r >> 4) * 4 + kq) * 16 + (r & 15))) * 8;
    }
    #pragma unroll
    for (int s = 0; s < 4; s++) {
        const int r = rr + s * 64;
        pb[s] = Bt + (long)(n0 + r) * ldb + kq * 8;
        oB[s] = swz((((r >> 4) * 4 + kq) * 16 + (r & 15))) * 8;
    }

    uint4 va[2], vb[4];
    #pragma unroll
    for (int s = 0; s < 2; s++) va[s] = *(const uint4*)(pa[s]);
    #pragma unroll
    for (int s = 0; s < 4; s++) vb[s] = *(const uint4*)(pb[s]);

    // frag chunk offsets (swizzled), precomputed
    int offA[4], offB[8];
    #pragma unroll
    for (int i = 0; i < 4; i++)
        offA[i] = swz((((wm >> 4) + i) * 4 + quad) * 16 + lm) * 8;
    #pragma unroll
    for (int j = 0; j < 8; j++)
        offB[j] = swz((((wn >> 4) + j) * 4 + quad) * 16 + lm) * 8;

    for (int k0 = 0; k0 < K; k0 += BK) {
        __syncthreads();               // prior readers done with LDS
        #pragma unroll
        for (int s = 0; s < 2; s++) *(uint4*)(&As[oA[s]]) = va[s];
        #pragma unroll
        for (int s = 0; s < 4; s++) *(uint4*)(&Bs[oB[s]]) = vb[s];
        __syncthreads();               // writes visible

        // prefetch next tile: loads fly across the MFMA phase below
        if (k0 + BK < K) {
            #pragma unroll
            for (int s = 0; s < 2; s++) va[s] = *(const uint4*)(pa[s] + k0 + BK);
            #pragma unroll
            for (int s = 0; s < 4; s++) vb[s] = *(const uint4*)(pb[s] + k0 + BK);
        }

        bf16x8 af[4], bfr[8];
        #pragma unroll
        for (int i = 0; i < 4; i++) af[i]  = *(const bf16x8*)(&As[offA[i]]);
        #pragma unroll
        for (int j = 0; j < 8; j++) bfr[j] = *(const bf16x8*)(&Bs[offB[j]]);
        #pragma unroll
        for (int i = 0; i < 4; i++)
            #pragma unroll
            for (int j = 0; j < 8; j++)
                acc[i][j] = __builtin_amdgcn_mfma_f32_16x16x32_bf16(
                    af[i], bfr[j], acc[i][j], 0, 0, 0);
    }

    // epilogue: C/D layout col=lane&15, row=quad*4+reg (m89-verified).
    // Transposed-packed: 4 consecutive m per lane -> one 8B store (r4-proven).
    #pragma unroll
    for (int i = 0; i < 4; i++) {
        const int row = m0 + wm + i * 16 + quad * 4;
        #pragma unroll
        for (int j = 0; j < 8; j++) {
            const int col = n0 + wn + j * 16 + lm;
            unsigned long long pk = 0;
            #pragma unroll
            for (int r = 0; r < 4; r++) {
                const float b = bias ? bf2f(bias[row + r]) : 0.f;
                pk |= (unsigned long long)f2bf((acc[i][j][r] + b) * scale) << (16 * r);
            }
            *(unsigned long long*)(&C[(long)col * ldc + row]) = pk;
        }
    }
}

// ---------- softmax ----------
__global__ __launch_bounds__(256) void softmax_rows(unsigned short* __restrict__ S, int rowlen) {
    __shared__ float red[4];
    const long row = blockIdx.x;
    unsigned short* p = S + row * rowlen;
    const int t = threadIdx.x;
    const int wave = t >> 6, lane = t & 63;

    uint4 raw = *(uint4*)(p + t * 8);
    unsigned short* u = (unsigned short*)&raw;
    float v[8], mx = -3.0e38f;
    #pragma unroll
    for (int i = 0; i < 8; i++) { v[i] = bf2f(u[i]); mx = fmaxf(mx, v[i]); }
    #pragma unroll
    for (int off = 32; off; off >>= 1) mx = fmaxf(mx, __shfl_down(mx, off));
    if (lane == 0) red[wave] = mx;
    __syncthreads();
    mx = fmaxf(fmaxf(red[0], red[1]), fmaxf(red[2], red[3]));
    __syncthreads();

    float s = 0.f;
    #pragma unroll
    for (int i = 0; i < 8; i++) { v[i] = __expf(v[i] - mx); s += v[i]; }
    #pragma unroll
    for (int off = 32; off; off >>= 1) s += __shfl_down(s, off);
    if (lane == 0) red[wave] = s;
    __syncthreads();
    s = red[0] + red[1] + red[2] + red[3];
    const float inv = 1.f / s;
    #pragma unroll
    for (int i = 0; i < 8; i++) u[i] = f2bf(v[i] * inv);
    *(uint4*)(p + t * 8) = raw;
}

// ---------- residual + LayerNorm, dual dtype ----------
__global__ __launch_bounds__(256) void resid_ln(
    const void* __restrict__ x, const unsigned short* __restrict__ attn,
    const void* __restrict__ gamma, const void* __restrict__ beta,
    void* __restrict__ out, const int* __restrict__ flag) {
    __shared__ float red[8];
    const long row = blockIdx.x;
    const int t = threadIdx.x;
    const int wave = t >> 6, lane = t & 63;
    const long base = row * 1024 + t * 4;
    const int f = *flag;

    uint2 ar = *(const uint2*)(attn + base);
    const unsigned short* au = (const unsigned short*)&ar;
    float h[4], s = 0.f, s2 = 0.f;
    if (f) {
        const float4 xr = *(const float4*)((const float*)x + base);
        h[0] = xr.x + bf2f(au[0]); h[1] = xr.y + bf2f(au[1]);
        h[2] = xr.z + bf2f(au[2]); h[3] = xr.w + bf2f(au[3]);
    } else {
        const uint2 xr = *(const uint2*)((const unsigned short*)x + base);
        const unsigned short* xu = (const unsigned short*)&xr;
        #pragma unroll
        for (int i = 0; i < 4; i++) h[i] = bf2f(xu[i]) + bf2f(au[i]);
    }
    #pragma unroll
    for (int i = 0; i < 4; i++) { s += h[i]; s2 += h[i] * h[i]; }
    #pragma unroll
    for (int off = 32; off; off >>= 1) { s += __shfl_down(s, off); s2 += __shfl_down(s2, off); }
    if (lane == 0) { red[wave] = s; red[4 + wave] = s2; }
    __syncthreads();
    s  = red[0] + red[1] + red[2] + red[3];
    s2 = red[4] + red[5] + red[6] + red[7];
    const float mu = s * (1.f / 1024.f);
    const float var = s2 * (1.f / 1024.f) - mu * mu;
    const float rstd = rsqrtf(var + 1e-3f);

    float g[4], bb[4];
    if (f) {
        const float4 gr = *(const float4*)((const float*)gamma + t * 4);
        const float4 br = *(const float4*)((const float*)beta  + t * 4);
        g[0]=gr.x; g[1]=gr.y; g[2]=gr.z; g[3]=gr.w;
        bb[0]=br.x; bb[1]=br.y; bb[2]=br.z; bb[3]=br.w;
    } else {
        #pragma unroll
        for (int i = 0; i < 4; i++) {
            g[i]  = bf2f(((const unsigned short*)gamma)[t * 4 + i]);
            bb[i] = bf2f(((const unsigned short*)beta)[t * 4 + i]);
        }
    }

    if (f) {
        float4 o;
        o.x = g[0]*(h[0]-mu)*rstd + bb[0];
        o.y = g[1]*(h[1]-mu)*rstd + bb[1];
        o.z = g[2]*(h[2]-mu)*rstd + bb[2];
        o.w = g[3]*(h[3]-mu)*rstd + bb[3];
        *(float4*)((float*)out + base) = o;
    } else {
        unsigned long long pk = 0;
        #pragma unroll
        for (int i = 0; i < 4; i++)
            pk |= (unsigned long long)f2bf(g[i]*(h[i]-mu)*rstd + bb[i]) << (16 * i);
        *(unsigned long long*)((unsigned short*)out + base) = pk;
    }
}

// ---------- launch ----------
extern "C" void kernel_launch(void* const* d_in, const int* in_sizes, int n_in,
                              void* d_out, int out_size, void* d_ws, size_t ws_size,
                              hipStream_t stream) {
    const void* x  = d_in[0];
    const void* Wq = d_in[1];
    const void* bq = d_in[2];
    const void* Wk = d_in[3];
    const void* bk = d_in[4];
    const void* Wv = d_in[5];
    const void* bv = d_in[6];
    const void* gamma = d_in[7];
    const void* beta  = d_in[8];

    // ws layout (bytes):
    //   xb / attn (reused):  0          (16,777,216)
    //   wt (Wq^T,Wk^T,Wv^T): 16,777,216 ( 6,291,456)
    //   bb (bq,bk,bv bf16):  23,068,672 (     6,144)
    //   flag:                23,074,816 (       128)
    //   qk [8192][2048]:     23,074,944 (33,554,432)  cols 0-1023=q, 1024-2047=k
    //   vt [1024][8192]:     56,629,376 (16,777,216)
    //   sc [4][2048][2048]:  73,406,592 (33,554,432)  -> end 106,961,024
    char* ws = (char*)d_ws;
    unsigned short* xb   = (unsigned short*)(ws);
    unsigned short* attn = (unsigned short*)(ws);
    unsigned short* wt   = (unsigned short*)(ws + 16777216L);
    unsigned short* bb   = (unsigned short*)(ws + 23068672L);
    int*            flag = (int*)(ws + 23074816L);
    unsigned short* qk   = (unsigned short*)(ws + 23074944L);
    unsigned short* vt   = (unsigned short*)(ws + 56629376L);
    unsigned short* sc   = (unsigned short*)(ws + 73406592L);

    const dim3 tb(256);
    detect_dtype<<<dim3(1), tb, 0, stream>>>((const unsigned short*)x, flag);
    convert_x<<<dim3(8192), tb, 0, stream>>>(x, xb, flag);
    transpose_convert<<<dim3(32, 32), tb, 0, stream>>>(Wq, wt, flag);
    transpose_convert<<<dim3(32, 32), tb, 0, stream>>>(Wk, wt + 1048576, flag);
    transpose_convert<<<dim3(32, 32), tb, 0, stream>>>(Wv, wt + 2097152, flag);
    convert_vec1024<<<dim3(1), tb, 0, stream>>>(bq, bb, flag);
    convert_vec1024<<<dim3(1), tb, 0, stream>>>(bk, bb + 1024, flag);
    convert_vec1024<<<dim3(1), tb, 0, stream>>>(bv, bb + 2048, flag);

    // Fused Q+K projection: qk[s][e'] = x @ [Wq|Wk] + [bq|bk]
    //   m = e' (2048), n = s (8192)
    gemm_bt<<<dim3(32, 16, 1), tb, 0, stream>>>(wt, xb, qk,
        1024, 1024, 1024, 2048, 0L, 0L, 0L, bb, 1.0f);
    // V projection (transposed out): vt[d][s] = (x @ Wv)^T; m = s, n = d
    gemm_bt<<<dim3(4, 64, 1), tb, 0, stream>>>(xb, wt + 2097152, vt,
        1024, 1024, 1024, 8192, 0L, 0L, 0L, nullptr, 1.0f);
    // scores: sc[z][q][k] = (q_z . k_z) / 32; m = k (2048), n = q (2048)
    gemm_bt<<<dim3(8, 16, 4), tb, 0, stream>>>(qk + 1024, qk, sc,
        1024, 2048, 2048, 2048, 4194304L, 4194304L, 4194304L, nullptr, 0.03125f);
    // P = softmax(sc) rows, in place
    softmax_rows<<<dim3(8192), tb, 0, stream>>>(sc, 2048);
    // attn[q][d] = P_z @ v_z + bv; m = d (1024), n = q (2048)
    gemm_bt<<<dim3(8, 8, 4), tb, 0, stream>>>(vt, sc, attn,
        2048, 8192, 2048, 1024, 2048L, 4194304L, 2097152L, bb + 2048, 1.0f);
    // out = LN(x + attn)
    resid_ln<<<dim3(8192), tb, 0, stream>>>(x, attn, gamma, beta, d_out, flag);
}

// Round 7
// 337.215 us; speedup vs baseline: 2.4146x; 1.7887x over previous
//
#include <hip/hip_runtime.h>

// ---------- types ----------
typedef __attribute__((ext_vector_type(8))) short bf16x8;   // 8 bf16 = 4 VGPRs
typedef __attribute__((ext_vector_type(4))) float f32x4;    // MFMA 16x16 acc

__device__ __forceinline__ unsigned short f2bf(float f) {
    union { float f; unsigned int u; } v; v.f = f;
    unsigned int u = v.u;
    u += 0x7fffu + ((u >> 16) & 1u);   // round-to-nearest-even
    return (unsigned short)(u >> 16);
}
__device__ __forceinline__ float bf2f(unsigned short s) {
    union { unsigned int u; float f; } v; v.u = ((unsigned int)s) << 16;
    return v.f;
}
// LDS chunk-index swizzle (r4-proven: 0 conflicts for staging writes AND frag reads)
__device__ __forceinline__ int swz(int p) { return p ^ ((p >> 3) & 7); }

// ---------- dtype probe: flag=1 if inputs are fp32, 0 if bf16 ----------
__global__ __launch_bounds__(256) void detect_dtype(
    const unsigned short* __restrict__ x, int* __restrict__ flag) {
    __shared__ int red[4];
    const int t = threadIdx.x;
    int cnt = 0;
    #pragma unroll
    for (int i = 0; i < 16; i++) {
        const unsigned short v = x[t * 16 + i];
        const int e = (v >> 7) & 0xFF;
        cnt += (e >= 0xC8) ? 1 : 0;
    }
    #pragma unroll
    for (int off = 32; off; off >>= 1) cnt += __shfl_down(cnt, off);
    if ((t & 63) == 0) red[t >> 6] = cnt;
    __syncthreads();
    if (t == 0) *flag = (red[0] + red[1] + red[2] + red[3] >= 16) ? 1 : 0;
}

// ---------- x -> bf16 copy/convert ----------
__global__ __launch_bounds__(256) void convert_x(
    const void* __restrict__ xin, unsigned short* __restrict__ xb,
    const int* __restrict__ flag) {
    const long i = ((long)blockIdx.x * 256 + threadIdx.x) * 4;
    if (*flag) {
        const float4 v = *(const float4*)((const float*)xin + i);
        unsigned long long pk =  (unsigned long long)f2bf(v.x)
                              | ((unsigned long long)f2bf(v.y) << 16)
                              | ((unsigned long long)f2bf(v.z) << 32)
                              | ((unsigned long long)f2bf(v.w) << 48);
        *(unsigned long long*)(xb + i) = pk;
    } else {
        *(unsigned long long*)(xb + i) =
            *(const unsigned long long*)((const unsigned short*)xin + i);
    }
}

// ---------- weight transpose+convert ----------
__global__ __launch_bounds__(256) void transpose_convert(
    const void* __restrict__ W, unsigned short* __restrict__ Wt,
    const int* __restrict__ flag) {
    __shared__ unsigned short tile[32][33];
    const int tx = threadIdx.x & 31, ty = threadIdx.x >> 5;
    const int x0 = blockIdx.x * 32, y0 = blockIdx.y * 32;
    const int f = *flag;
    #pragma unroll
    for (int i = 0; i < 32; i += 8) {
        const long idx = (long)(y0 + ty + i) * 1024 + x0 + tx;
        tile[ty + i][tx] = f ? f2bf(((const float*)W)[idx])
                             : ((const unsigned short*)W)[idx];
    }
    __syncthreads();
    #pragma unroll
    for (int i = 0; i < 32; i += 8)
        Wt[(long)(x0 + ty + i) * 1024 + y0 + tx] = tile[tx][ty + i];
}

// ---------- 1024-vec -> bf16 ----------
__global__ __launch_bounds__(256) void convert_vec1024(
    const void* __restrict__ in, unsigned short* __restrict__ outv,
    const int* __restrict__ flag) {
    const int i = threadIdx.x * 4;
    if (*flag) {
        const float4 v = *(const float4*)((const float*)in + i);
        outv[i] = f2bf(v.x); outv[i+1] = f2bf(v.y);
        outv[i+2] = f2bf(v.z); outv[i+3] = f2bf(v.w);
    } else {
        *(unsigned long long*)(outv + i) =
            *(const unsigned long long*)((const unsigned short*)in + i);
    }
}

// ---------- bf16 GEMM: r4 structure + double-buffered LDS (1 barrier/iter) ----
// C[n][m] = scale * (sum_k A[m][k]*Bt[n][k] + bias[m])   (bias row-indexed)
// 128x128 tile, 4 waves (2x2), 4x4 MFMA 16x16x32 per wave. Software pipeline:
// iter k writes tile k+1 (loaded last iter) to spare buffer, issues loads for
// tile k+2, computes tile k, single __syncthreads(). Load->use window = 1 iter.
#define BM 128
#define BN 128
#define BK 32

__global__ __launch_bounds__(256) void gemm_bt(
    const unsigned short* __restrict__ A, const unsigned short* __restrict__ Bt,
    unsigned short* __restrict__ C,
    int K, int lda, int ldb, int ldc,
    long strideAz, long strideBz, long strideCz,
    const unsigned short* __restrict__ bias, float scale) {

    A  += (long)blockIdx.z * strideAz;
    Bt += (long)blockIdx.z * strideBz;
    C  += (long)blockIdx.z * strideCz;

    __shared__ unsigned short As[2 * BM * BK];   // 2 x 8 KiB
    __shared__ unsigned short Bs[2 * BN * BK];   // 2 x 8 KiB

    const int t    = threadIdx.x;
    const int wave = t >> 6;
    const int lane = t & 63;
    const int quad = lane >> 4;
    const int lm   = lane & 15;

    const int m0 = blockIdx.y * BM;
    const int n0 = blockIdx.x * BN;
    const int wm = (wave >> 1) * 64;
    const int wn = (wave & 1) * 64;

    f32x4 acc[4][4];
    #pragma unroll
    for (int i = 0; i < 4; i++)
        #pragma unroll
        for (int j = 0; j < 4; j++) acc[i][j] = (f32x4){0.f, 0.f, 0.f, 0.f};

    // staging: thread t handles chunks c0=t (row r0, kq), c1=t+256 (row r0+64, kq)
    const int r0 = t >> 2, kq = t & 3;
    const int r1 = r0 + 64;
    const int p0 = swz(((r0 >> 4) * 4 + kq) * 16 + (r0 & 15)) * 8;
    const int p1 = swz(((r1 >> 4) * 4 + kq) * 16 + (r1 & 15)) * 8;

    const unsigned short* pa0 = A  + (long)(m0 + r0) * lda + kq * 8;
    const unsigned short* pa1 = A  + (long)(m0 + r1) * lda + kq * 8;
    const unsigned short* pb0 = Bt + (long)(n0 + r0) * ldb + kq * 8;
    const unsigned short* pb1 = Bt + (long)(n0 + r1) * ldb + kq * 8;

    // frag chunk offsets (swizzled), precomputed
    int offA[4], offB[4];
    #pragma unroll
    for (int i = 0; i < 4; i++) {
        offA[i] = swz((((wm >> 4) + i) * 4 + quad) * 16 + lm) * 8;
        offB[i] = swz((((wn >> 4) + i) * 4 + quad) * 16 + lm) * 8;
    }

    // ---- pipeline prologue: tile0 -> buf0; tile1 -> regs ----
    uint4 va0 = *(const uint4*)(pa0);
    uint4 va1 = *(const uint4*)(pa1);
    uint4 vb0 = *(const uint4*)(pb0);
    uint4 vb1 = *(const uint4*)(pb1);
    *(uint4*)(&As[p0]) = va0;  *(uint4*)(&As[p1]) = va1;
    *(uint4*)(&Bs[p0]) = vb0;  *(uint4*)(&Bs[p1]) = vb1;
    if (BK < K) {
        va0 = *(const uint4*)(pa0 + BK);
        va1 = *(const uint4*)(pa1 + BK);
        vb0 = *(const uint4*)(pb0 + BK);
        vb1 = *(const uint4*)(pb1 + BK);
    }
    __syncthreads();

    for (int k0 = 0; k0 < K; k0 += BK) {
        const int cb = (k0 >> 5) & 1;            // current buffer
        unsigned short* Ac = As + cb * (BM * BK);
        unsigned short* Bc = Bs + cb * (BN * BK);
        unsigned short* An = As + (cb ^ 1) * (BM * BK);
        unsigned short* Bn = Bs + (cb ^ 1) * (BN * BK);

        // write tile k+1 (regs, loaded last iter) into the spare buffer
        if (k0 + BK < K) {
            *(uint4*)(&An[p0]) = va0;  *(uint4*)(&An[p1]) = va1;
            *(uint4*)(&Bn[p0]) = vb0;  *(uint4*)(&Bn[p1]) = vb1;
        }
        // issue loads for tile k+2 (full-iteration flight time)
        if (k0 + 2 * BK < K) {
            va0 = *(const uint4*)(pa0 + k0 + 2 * BK);
            va1 = *(const uint4*)(pa1 + k0 + 2 * BK);
            vb0 = *(const uint4*)(pb0 + k0 + 2 * BK);
            vb1 = *(const uint4*)(pb1 + k0 + 2 * BK);
        }

        // compute tile k from the current buffer
        bf16x8 af[4], bfr[4];
        #pragma unroll
        for (int i = 0; i < 4; i++) {
            af[i]  = *(const bf16x8*)(&Ac[offA[i]]);
            bfr[i] = *(const bf16x8*)(&Bc[offB[i]]);
        }
        #pragma unroll
        for (int i = 0; i < 4; i++)
            #pragma unroll
            for (int j = 0; j < 4; j++)
                acc[i][j] = __builtin_amdgcn_mfma_f32_16x16x32_bf16(
                    af[i], bfr[j], acc[i][j], 0, 0, 0);

        __syncthreads();   // everyone done reading cur + writing spare
    }

    // epilogue: C/D layout col=lane&15, row=quad*4+reg (m89-verified).
    // Transposed-packed: 4 consecutive m per lane -> one 8B store (r4-proven).
    #pragma unroll
    for (int i = 0; i < 4; i++) {
        const int row = m0 + wm + i * 16 + quad * 4;
        #pragma unroll
        for (int j = 0; j < 4; j++) {
            const int col = n0 + wn + j * 16 + lm;
            unsigned long long pk = 0;
            #pragma unroll
            for (int r = 0; r < 4; r++) {
                const float b = bias ? bf2f(bias[row + r]) : 0.f;
                pk |= (unsigned long long)f2bf((acc[i][j][r] + b) * scale) << (16 * r);
            }
            *(unsigned long long*)(&C[(long)col * ldc + row]) = pk;
        }
    }
}

// ---------- softmax ----------
__global__ __launch_bounds__(256) void softmax_rows(unsigned short* __restrict__ S, int rowlen) {
    __shared__ float red[4];
    const long row = blockIdx.x;
    unsigned short* p = S + row * rowlen;
    const int t = threadIdx.x;
    const int wave = t >> 6, lane = t & 63;

    uint4 raw = *(uint4*)(p + t * 8);
    unsigned short* u = (unsigned short*)&raw;
    float v[8], mx = -3.0e38f;
    #pragma unroll
    for (int i = 0; i < 8; i++) { v[i] = bf2f(u[i]); mx = fmaxf(mx, v[i]); }
    #pragma unroll
    for (int off = 32; off; off >>= 1) mx = fmaxf(mx, __shfl_down(mx, off));
    if (lane == 0) red[wave] = mx;
    __syncthreads();
    mx = fmaxf(fmaxf(red[0], red[1]), fmaxf(red[2], red[3]));
    __syncthreads();

    float s = 0.f;
    #pragma unroll
    for (int i = 0; i < 8; i++) { v[i] = __expf(v[i] - mx); s += v[i]; }
    #pragma unroll
    for (int off = 32; off; off >>= 1) s += __shfl_down(s, off);
    if (lane == 0) red[wave] = s;
    __syncthreads();
    s = red[0] + red[1] + red[2] + red[3];
    const float inv = 1.f / s;
    #pragma unroll
    for (int i = 0; i < 8; i++) u[i] = f2bf(v[i] * inv);
    *(uint4*)(p + t * 8) = raw;
}

// ---------- residual + LayerNorm, dual dtype ----------
__global__ __launch_bounds__(256) void resid_ln(
    const void* __restrict__ x, const unsigned short* __restrict__ attn,
    const void* __restrict__ gamma, const void* __restrict__ beta,
    void* __restrict__ out, const int* __restrict__ flag) {
    __shared__ float red[8];
    const long row = blockIdx.x;
    const int t = threadIdx.x;
    const int wave = t >> 6, lane = t & 63;
    const long base = row * 1024 + t * 4;
    const int f = *flag;

    uint2 ar = *(const uint2*)(attn + base);
    const unsigned short* au = (const unsigned short*)&ar;
    float h[4], s = 0.f, s2 = 0.f;
    if (f) {
        const float4 xr = *(const float4*)((const float*)x + base);
        h[0] = xr.x + bf2f(au[0]); h[1] = xr.y + bf2f(au[1]);
        h[2] = xr.z + bf2f(au[2]); h[3] = xr.w + bf2f(au[3]);
    } else {
        const uint2 xr = *(const uint2*)((const unsigned short*)x + base);
        const unsigned short* xu = (const unsigned short*)&xr;
        #pragma unroll
        for (int i = 0; i < 4; i++) h[i] = bf2f(xu[i]) + bf2f(au[i]);
    }
    #pragma unroll
    for (int i = 0; i < 4; i++) { s += h[i]; s2 += h[i] * h[i]; }
    #pragma unroll
    for (int off = 32; off; off >>= 1) { s += __shfl_down(s, off); s2 += __shfl_down(s2, off); }
    if (lane == 0) { red[wave] = s; red[4 + wave] = s2; }
    __syncthreads();
    s  = red[0] + red[1] + red[2] + red[3];
    s2 = red[4] + red[5] + red[6] + red[7];
    const float mu = s * (1.f / 1024.f);
    const float var = s2 * (1.f / 1024.f) - mu * mu;
    const float rstd = rsqrtf(var + 1e-3f);

    float g[4], bb[4];
    if (f) {
        const float4 gr = *(const float4*)((const float*)gamma + t * 4);
        const float4 br = *(const float4*)((const float*)beta  + t * 4);
        g[0]=gr.x; g[1]=gr.y; g[2]=gr.z; g[3]=gr.w;
        bb[0]=br.x; bb[1]=br.y; bb[2]=br.z; bb[3]=br.w;
    } else {
        #pragma unroll
        for (int i = 0; i < 4; i++) {
            g[i]  = bf2f(((const unsigned short*)gamma)[t * 4 + i]);
            bb[i] = bf2f(((const unsigned short*)beta)[t * 4 + i]);
        }
    }

    if (f) {
        float4 o;
        o.x = g[0]*(h[0]-mu)*rstd + bb[0];
        o.y = g[1]*(h[1]-mu)*rstd + bb[1];
        o.z = g[2]*(h[2]-mu)*rstd + bb[2];
        o.w = g[3]*(h[3]-mu)*rstd + bb[3];
        *(float4*)((float*)out + base) = o;
    } else {
        unsigned long long pk = 0;
        #pragma unroll
        for (int i = 0; i < 4; i++)
            pk |= (unsigned long long)f2bf(g[i]*(h[i]-mu)*rstd + bb[i]) << (16 * i);
        *(unsigned long long*)((unsigned short*)out + base) = pk;
    }
}

// ---------- launch ----------
extern "C" void kernel_launch(void* const* d_in, const int* in_sizes, int n_in,
                              void* d_out, int out_size, void* d_ws, size_t ws_size,
                              hipStream_t stream) {
    const void* x  = d_in[0];
    const void* Wq = d_in[1];
    const void* bq = d_in[2];
    const void* Wk = d_in[3];
    const void* bk = d_in[4];
    const void* Wv = d_in[5];
    const void* bv = d_in[6];
    const void* gamma = d_in[7];
    const void* beta  = d_in[8];

    // ws layout (bytes):
    //   xb / attn (reused):  0          (16,777,216)
    //   wt (Wq^T,Wk^T,Wv^T): 16,777,216 ( 6,291,456)
    //   bb (bq,bk,bv bf16):  23,068,672 (     6,144)
    //   flag:                23,074,816 (       128)
    //   qk [8192][2048]:     23,074,944 (33,554,432)  cols 0-1023=q, 1024-2047=k
    //   vt [1024][8192]:     56,629,376 (16,777,216)
    //   sc [4][2048][2048]:  73,406,592 (33,554,432)  -> end 106,961,024
    char* ws = (char*)d_ws;
    unsigned short* xb   = (unsigned short*)(ws);
    unsigned short* attn = (unsigned short*)(ws);
    unsigned short* wt   = (unsigned short*)(ws + 16777216L);
    unsigned short* bb   = (unsigned short*)(ws + 23068672L);
    int*            flag = (int*)(ws + 23074816L);
    unsigned short* qk   = (unsigned short*)(ws + 23074944L);
    unsigned short* vt   = (unsigned short*)(ws + 56629376L);
    unsigned short* sc   = (unsigned short*)(ws + 73406592L);

    const dim3 tb(256);
    detect_dtype<<<dim3(1), tb, 0, stream>>>((const unsigned short*)x, flag);
    convert_x<<<dim3(8192), tb, 0, stream>>>(x, xb, flag);
    transpose_convert<<<dim3(32, 32), tb, 0, stream>>>(Wq, wt, flag);
    transpose_convert<<<dim3(32, 32), tb, 0, stream>>>(Wk, wt + 1048576, flag);
    transpose_convert<<<dim3(32, 32), tb, 0, stream>>>(Wv, wt + 2097152, flag);
    convert_vec1024<<<dim3(1), tb, 0, stream>>>(bq, bb, flag);
    convert_vec1024<<<dim3(1), tb, 0, stream>>>(bk, bb + 1024, flag);
    convert_vec1024<<<dim3(1), tb, 0, stream>>>(bv, bb + 2048, flag);

    // Fused Q+K projection: qk[s][e'] = x @ [Wq|Wk] + [bq|bk]; m = e', n = s
    gemm_bt<<<dim3(64, 16, 1), tb, 0, stream>>>(wt, xb, qk,
        1024, 1024, 1024, 2048, 0L, 0L, 0L, bb, 1.0f);
    // V projection (transposed out): vt[d][s] = (x @ Wv)^T; m = s, n = d
    gemm_bt<<<dim3(8, 64, 1), tb, 0, stream>>>(xb, wt + 2097152, vt,
        1024, 1024, 1024, 8192, 0L, 0L, 0L, nullptr, 1.0f);
    // scores: sc[z][q][k] = (q_z . k_z) / 32; m = k, n = q
    gemm_bt<<<dim3(16, 16, 4), tb, 0, stream>>>(qk + 1024, qk, sc,
        1024, 2048, 2048, 2048, 4194304L, 4194304L, 4194304L, nullptr, 0.03125f);
    // P = softmax(sc) rows, in place
    softmax_rows<<<dim3(8192), tb, 0, stream>>>(sc, 2048);
    // attn[q][d] = P_z @ v_z + bv; m = d, n = q
    gemm_bt<<<dim3(16, 8, 4), tb, 0, stream>>>(vt, sc, attn,
        2048, 8192, 2048, 1024, 2048L, 4194304L, 2097152L, bb + 2048, 1.0f);
    // out = LN(x + attn)
    resid_ln<<<dim3(8192), tb, 0, stream>>>(x, attn, gamma, beta, d_out, flag);
}